// Round 11
// baseline (247.695 us; speedup 1.0000x reference)
//
#include <hip/hip_runtime.h>

#define SEQ   2048
#define NHEADS 16
#define HDIM  64
#define HID   1024
#define ROT   32

typedef __attribute__((ext_vector_type(8))) short  short8;
typedef __attribute__((ext_vector_type(4))) float  floatx4;

__device__ __forceinline__ ushort f2bf(float f) {
    union { float f; uint u; } v; v.f = f;
    uint x = v.u;
    uint r = (x + 0x7FFFu + ((x >> 16) & 1u)) >> 16;
    return (ushort)r;
}

__device__ __forceinline__ float fexp2(float x) {
    return __builtin_amdgcn_exp2f(x);     // v_exp_f32 directly
}

__device__ __forceinline__ floatx4 mfma_bf16(short8 a, short8 b, floatx4 c) {
    return __builtin_amdgcn_mfma_f32_16x16x32_bf16(a, b, c, 0, 0, 0);
}

__device__ __forceinline__ void gload16(const ushort* g, ushort* l) {
    __builtin_amdgcn_global_load_lds(
        (const __attribute__((address_space(1))) void*)g,
        (__attribute__((address_space(3))) void*)l, 16, 0, 0);
}

// ---------------------------------------------------------------------------
// Pre-pass A: fp32 -> bf16 elementwise (hidden)
// ---------------------------------------------------------------------------
__global__ __launch_bounds__(256) void convert_bf16_kernel(
    const float* __restrict__ src, ushort* __restrict__ dst, int n)
{
    int i = (blockIdx.x * 256 + threadIdx.x) * 8;
    if (i >= n) return;
    float4 a = *(const float4*)(src + i);
    float4 b = *(const float4*)(src + i + 4);
    short8 v;
    v[0] = (short)f2bf(a.x); v[1] = (short)f2bf(a.y);
    v[2] = (short)f2bf(a.z); v[3] = (short)f2bf(a.w);
    v[4] = (short)f2bf(b.x); v[5] = (short)f2bf(b.y);
    v[6] = (short)f2bf(b.z); v[7] = (short)f2bf(b.w);
    *(short8*)(dst + i) = v;
}

// ---------------------------------------------------------------------------
// Pre-pass B: fp32 (K,N) -> bf16 (N,K) transpose-convert. Tile 64x64.
// ---------------------------------------------------------------------------
__global__ __launch_bounds__(256) void transpose_bf16_kernel(
    const float* __restrict__ src, ushort* __restrict__ dst, int K, int N)
{
    __shared__ ushort Tl[64 * 68];
    const int k0 = blockIdx.y * 64, n0 = blockIdx.x * 64;
    const int tid = threadIdx.x;
    #pragma unroll
    for (int i = 0; i < 4; i++) {
        int lin = tid + 256 * i;
        int row = lin >> 4;
        int c4  = (lin & 15) * 4;
        float4 v = *(const float4*)(src + (size_t)(k0 + row) * N + n0 + c4);
        uint2 u;
        u.x = (uint)f2bf(v.x) | ((uint)f2bf(v.y) << 16);
        u.y = (uint)f2bf(v.z) | ((uint)f2bf(v.w) << 16);
        *(uint2*)&Tl[row * 68 + c4] = u;
    }
    __syncthreads();
    #pragma unroll
    for (int j = 0; j < 2; j++) {
        int lin = tid + 256 * j;
        int n = lin >> 3, c = lin & 7;
        short8 v;
        #pragma unroll
        for (int u = 0; u < 8; u++) v[u] = (short)Tl[(c * 8 + u) * 68 + n];
        *(short8*)(dst + (size_t)(n0 + n) * K + k0 + c * 8) = v;
    }
}

// ---------------------------------------------------------------------------
// Kernel 1: qkv = hidden @ w_qkv (M=4096, N=3072, K=1024) bf16 inputs.
// 256x128 tile, 8 waves (512 thr), BK=32, round-9 2-phase pipelined
// double-buffer (issue next tile's gload_lds before compute, vmcnt(0)+
// raw barrier per iter). Staging traffic/FLOP = 0.75x of the 128^2 tile;
// 3 gload16/thread/iter. LDS 48KB -> 3 blocks/CU x 8 waves = 24 waves/CU.
// Fused RoPE + head split. Q pre-scaled by 0.125*log2(e).
// Q,K (b,h,s,d); V (b,h,d,s).
// ---------------------------------------------------------------------------
__global__ __launch_bounds__(512, 6) void qkv_rope_kernel(
    const ushort* __restrict__ hbf,     // (4096,1024) bf16
    const ushort* __restrict__ wqkvT,   // (3072,1024) bf16 (N,K)
    ushort* __restrict__ Qb, ushort* __restrict__ Kb, ushort* __restrict__ Vb)
{
    __shared__ ushort Al[2][8192];      // A tile 256x32
    __shared__ ushort Bl[2][4096];      // B tile 128x32
    const int tid  = threadIdx.x;
    const int lane = tid & 63;
    const int wv   = tid >> 6;          // 0..7
    const int g    = lane >> 4;
    const int l15  = lane & 15;

    // XCD-chunked remap over the 24(n) x 16(m) grid: each XCD owns a
    // 12(n) x 4(m) chunk (A 2MB + B 3MB ~ L2-resident).
    const int lin  = blockIdx.x + 24 * blockIdx.y;  // 0..383
    const int xcd  = lin & 7;
    const int slot = lin >> 3;                      // 0..47
    const int cxi  = xcd & 1, cyi = xcd >> 1;       // 2 x 4 chunks
    const int sx   = slot % 12, sy = slot / 12;     // 12 x 4
    const int n0   = (cxi * 12 + sx) * 128;
    const int m0   = (cyi * 4 + sy) * 256;

    const int wr = (wv >> 1) * 64;      // 0..192 (4 m-waves)
    const int wc = (wv & 1) * 64;       // 0,64   (2 n-waves)
    const int rowl = lane >> 2;         // 0..15
    const int kcol = (lane & 3) * 8;

    floatx4 acc[4][4];
    #pragma unroll
    for (int a = 0; a < 4; a++)
        #pragma unroll
        for (int bq = 0; bq < 4; bq++)
            acc[a][bq] = floatx4{0.f, 0.f, 0.f, 0.f};

    // A: wave wv stages rows [m0+wv*32, +32) (2 loads); B: rows [n0+wv*16,+16)
    const ushort* ga = hbf   + (size_t)(m0 + wv * 32 + rowl) * 1024 + kcol;
    const ushort* gb = wqkvT + (size_t)(n0 + wv * 16 + rowl) * 1024 + kcol;
    const int lofsA = wv * 1024;        // ushorts (2 x 512 segments)
    const int lofsB = wv * 512;

    auto stage = [&](int t, int buf) {
        const int k0 = t * 32;
        gload16(ga + k0,             &Al[buf][lofsA]);
        gload16(ga + k0 + 16 * 1024, &Al[buf][lofsA + 512]);
        gload16(gb + k0,             &Bl[buf][lofsB]);
    };

    stage(0, 0);
    asm volatile("s_waitcnt vmcnt(0)" ::: "memory");
    __builtin_amdgcn_s_barrier();

    for (int it = 0; it < 32; it++) {
        const int cur = it & 1;
        if (it + 1 < 32) stage(it + 1, cur ^ 1);
        short8 af[4], bfr[4];
        #pragma unroll
        for (int fm = 0; fm < 4; fm++)
            af[fm] = *(const short8*)&Al[cur][(wr + fm * 16 + l15) * 32 + g * 8];
        #pragma unroll
        for (int fn = 0; fn < 4; fn++)
            bfr[fn] = *(const short8*)&Bl[cur][(wc + fn * 16 + l15) * 32 + g * 8];
        #pragma unroll
        for (int fm = 0; fm < 4; fm++)
            #pragma unroll
            for (int fn = 0; fn < 4; fn++)
                acc[fm][fn] = mfma_bf16(af[fm], bfr[fn], acc[fm][fn]);
        asm volatile("s_waitcnt vmcnt(0)" ::: "memory");
        __builtin_amdgcn_s_barrier();
    }

    #pragma unroll
    for (int fn = 0; fn < 4; fn++) {
        const int c    = n0 + wc + fn * 16 + l15;
        const int mp   = c / 384;
        const int rem  = c - mp * 384;
        const int tsel = rem >> 7;                    // 0=q 1=k 2=v
        const int j    = (rem >> 6) & 1;
        const int d    = rem & 63;
        const int head = mp * 2 + j;
        ushort* basep = (tsel == 0) ? Qb : (tsel == 1) ? Kb : Vb;
        const bool rope = (tsel < 2) && (d < ROT);
        // Q carries 1/sqrt(64) * log2(e) so attention uses exp2 directly
        const float qscale = (tsel == 0) ? 0.18033688011112042f : 1.0f;
        float freq = 0.f;
        if (rope) {
            freq = exp2f((float)(d >> 1) * -0.830482023721841f);
        }
        #pragma unroll
        for (int fm = 0; fm < 4; fm++) {
            #pragma unroll
            for (int r = 0; r < 4; r++) {
                int row = m0 + wr + fm * 16 + g * 4 + r;
                int bb  = row >> 11;
                int s   = row & 2047;
                float val = acc[fm][fn][r];
                float pv  = __shfl_xor(val, 1, 64);
                float outv = val;
                if (rope) {
                    float ang = (float)s * freq;
                    float sn, cs;
                    __sincosf(ang, &sn, &cs);
                    outv = ((d & 1) == 0) ? (val * cs - pv * sn)
                                          : (val * cs + pv * sn);
                }
                outv *= qscale;
                size_t off;
                if (tsel == 2)
                    off = ((size_t)(bb * NHEADS + head) * HDIM + d) * SEQ + s;
                else
                    off = ((size_t)(bb * NHEADS + head) * SEQ + s) * HDIM + d;
                basep[off] = f2bf(outv);
            }
        }
    }
}

// ---------------------------------------------------------------------------
// Kernel 2: flash attention, causal. 512 threads = 8 waves x 16 q-rows
// (Q tile 128), KV tiles 64. Complementary-qb pairing; 2-deep register
// prefetch + LDS double-buffer; exp2-domain softmax with per-lane defer-max
// (cross-lane reduces only on rescale) and epilogue-deferred l-sum.
// ---------------------------------------------------------------------------
__global__ __launch_bounds__(512, 4) void attn_kernel(
    const ushort* __restrict__ Qb, const ushort* __restrict__ Kb,
    const ushort* __restrict__ Vb, ushort* __restrict__ attn)
{
    __shared__ ushort Kl[2][64 * 72];      // [key][d], stride 72
    __shared__ ushort Vt[2][64 * 72];      // [d][key], stride 72

    const int tid  = threadIdx.x;
    const int lane = tid & 63;
    const int wv   = tid >> 6;             // 0..7
    const int g    = lane >> 4;
    const int l15  = lane & 15;

    const int l    = blockIdx.x + 16 * blockIdx.y + 256 * blockIdx.z;
    const int half = l >> 8;
    const int xx   = l & 15;
    const int hh   = (l >> 4) & 15;
    const int qb   = half ? xx : 15 - xx;
    const int bb   = half;

    const int q0 = qb * 128;
    const int wq = wv * 16;
    const size_t kvbase = (size_t)(bb * NHEADS + hh) * SEQ * HDIM;

    const int srow = tid >> 3;             // 0..63 staging row
    const int sch  = (tid & 7) * 8;        // staging col (ushort)

    short8 qreg[2];
    #pragma unroll
    for (int ks = 0; ks < 2; ks++)
        qreg[ks] = *(const short8*)(Qb + kvbase +
            (size_t)(q0 + wq + l15) * HDIM + ks * 32 + g * 8);

    float m = -__builtin_inff();
    float lsum = 0.f;                      // per-lane partial (16 keys/row)
    floatx4 of[4];
    #pragma unroll
    for (int df = 0; df < 4; df++) of[df] = floatx4{0.f, 0.f, 0.f, 0.f};

    const int nt = 2 * qb + 2;             // always even

    auto load_tile = [&](int tt, short8& kr, short8& vr) {
        const int kv = tt * 64;
        kr = *(const short8*)(Kb + kvbase + (size_t)(kv + srow) * HDIM + sch);
        vr = *(const short8*)(Vb + kvbase + (size_t)srow * SEQ + kv + sch);
    };
    auto write_tile = [&](int buf, short8& kr, short8& vr) {
        *(short8*)&Kl[buf][srow * 72 + sch] = kr;
        *(short8*)&Vt[buf][srow * 72 + sch] = vr;
    };
    auto compute_tile = [&](int t, const ushort* Kc, const ushort* Vc) {
        const int kv0 = t * 64;
        if (kv0 > q0 + wq + 15) return;    // fully-masked for this wave
        // QK^T (swapped): sf[kf], lane l15 = q-row, key = kv0 + kf*16 + g*4 + r
        floatx4 sf[4];
        __builtin_amdgcn_s_setprio(1);
        #pragma unroll
        for (int kf = 0; kf < 4; kf++) {
            short8 kr0 = *(const short8*)&Kc[(kf * 16 + l15) * 72 + g * 8];
            short8 kr1 = *(const short8*)&Kc[(kf * 16 + l15) * 72 + 32 + g * 8];
            floatx4 s = floatx4{0.f, 0.f, 0.f, 0.f};
            s = mfma_bf16(kr0, qreg[0], s);
            s = mfma_bf16(kr1, qreg[1], s);
            sf[kf] = s;
        }
        __builtin_amdgcn_s_setprio(0);

        const bool diag = (kv0 + 63 > q0 + wq);   // wave-uniform
        const int qg = q0 + wq + l15;
        float tmax = -__builtin_inff();
        if (diag) {
            #pragma unroll
            for (int kf = 0; kf < 4; kf++) {
                #pragma unroll
                for (int r = 0; r < 4; r++) {
                    int key = kv0 + kf * 16 + g * 4 + r;
                    float x = sf[kf][r];
                    if (key > qg) x = -1e9f;
                    sf[kf][r] = x;
                    tmax = fmaxf(tmax, x);
                }
            }
        } else {
            #pragma unroll
            for (int kf = 0; kf < 4; kf++)
                #pragma unroll
                for (int r = 0; r < 4; r++)
                    tmax = fmaxf(tmax, sf[kf][r]);
        }
        // per-lane defer-max: no cross-lane traffic in the common case
        if (!__all(tmax <= m + 8.0f)) {
            tmax = fmaxf(tmax, __shfl_xor(tmax, 16, 64));
            tmax = fmaxf(tmax, __shfl_xor(tmax, 32, 64));
            float mn = fmaxf(m, tmax);
            float f  = fexp2(m - mn);
            m = mn;
            lsum *= f;
            #pragma unroll
            for (int r = 0; r < 4; r++) {
                float fr = __shfl(f, g * 4 + r, 64);
                #pragma unroll
                for (int df = 0; df < 4; df++)
                    of[df][r] *= fr;
            }
        }
        float rs = 0.f;
        #pragma unroll
        for (int kf = 0; kf < 4; kf++) {
            #pragma unroll
            for (int r = 0; r < 4; r++) {
                float p = fexp2(sf[kf][r] - m);
                sf[kf][r] = p;
                rs += p;
            }
        }
        lsum += rs;
        // pack P into lane-local A-frags via v_cvt_pk_bf16_f32
        short8 pa[2];
        #pragma unroll
        for (int ks = 0; ks < 2; ks++) {
            union { short8 s; uint u[4]; } pu;
            #pragma unroll
            for (int w = 0; w < 4; w++) {
                const int kf = 2 * ks + (w >> 1);
                float lo = sf[kf][(w & 1) * 2 + 0];
                float hi = sf[kf][(w & 1) * 2 + 1];
                asm("v_cvt_pk_bf16_f32 %0, %1, %2"
                    : "=v"(pu.u[w]) : "v"(lo), "v"(hi));
            }
            pa[ks] = pu.s;
        }
        // PV
        __builtin_amdgcn_s_setprio(1);
        #pragma unroll
        for (int df = 0; df < 4; df++) {
            #pragma unroll
            for (int ks = 0; ks < 2; ks++) {
                const int vb = (df * 16 + l15) * 72 + ks * 32 + g * 4;
                uint2 v0 = *(const uint2*)&Vc[vb];
                uint2 v1 = *(const uint2*)&Vc[vb + 16];
                union { short8 s; uint4 u; } vv;
                vv.u.x = v0.x; vv.u.y = v0.y; vv.u.z = v1.x; vv.u.w = v1.y;
                of[df] = mfma_bf16(pa[ks], vv.s, of[df]);
            }
        }
        __builtin_amdgcn_s_setprio(0);
    };

    short8 kA, vA, kB, vB;
    load_tile(0, kA, vA);
    if (nt > 1) load_tile(1, kB, vB);
    write_tile(0, kA, vA);
    __syncthreads();

    for (int t = 0; t < nt; t += 2) {
        if (t + 2 < nt) load_tile(t + 2, kA, vA);
        compute_tile(t, Kl[0], Vt[0]);
        write_tile(1, kB, vB);
        __syncthreads();
        if (t + 3 < nt) load_tile(t + 3, kB, vB);
        compute_tile(t + 1, Kl[1], Vt[1]);
        if (t + 2 < nt) write_tile(0, kA, vA);
        __syncthreads();
    }

    // epilogue: reduce l across g-lanes once, O /= l, store attn (b,s,H) bf16
    lsum += __shfl_xor(lsum, 16, 64);
    lsum += __shfl_xor(lsum, 32, 64);
    #pragma unroll
    for (int r = 0; r < 4; r++) {
        float lr = __shfl(lsum, g * 4 + r, 64);
        float inv = 1.0f / lr;
        int q = q0 + wq + g * 4 + r;
        #pragma unroll
        for (int df = 0; df < 4; df++)
            attn[((size_t)bb * SEQ + q) * HID + hh * 64 + df * 16 + l15] =
                f2bf(of[df][r] * inv);
    }
}

// ---------------------------------------------------------------------------
// Kernel 3: out = attn @ w_out (M=4096, N=1024, K=1024), 2-phase pipelined
// double-buffer (round-9 form), fp32 output.
// ---------------------------------------------------------------------------
__global__ __launch_bounds__(256) void out_proj_kernel(
    const ushort* __restrict__ attn,    // (4096,1024) bf16
    const ushort* __restrict__ woutT,   // (1024,1024) bf16 (N,K)
    float* __restrict__ out)
{
    __shared__ ushort Al[2][128 * 32];
    __shared__ ushort Bl[2][128 * 32];
    const int tid  = threadIdx.x;
    const int lane = tid & 63;
    const int wv   = tid >> 6;
    const int g    = lane >> 4;
    const int l15  = lane & 15;

    const int lin  = blockIdx.x + 8 * blockIdx.y;   // 0..255
    const int xcd  = lin & 7;
    const int slot = lin >> 3;                      // 0..31
    const int cxi  = xcd & 1, cyi = xcd >> 1;
    const int sx   = slot & 3, sy = slot >> 2;      // 4x8
    const int n0   = (cxi * 4 + sx) * 128;
    const int m0   = (cyi * 8 + sy) * 128;

    const int wr = (wv >> 1) * 64;
    const int wc = (wv & 1) * 64;
    const int rowl = lane >> 2;
    const int kcol = (lane & 3) * 8;

    floatx4 acc[4][4];
    #pragma unroll
    for (int a = 0; a < 4; a++)
        #pragma unroll
        for (int bq = 0; bq < 4; bq++)
            acc[a][bq] = floatx4{0.f, 0.f, 0.f, 0.f};

    const ushort* ga = attn  + (size_t)(m0 + wv * 32 + rowl) * 1024 + kcol;
    const ushort* gb = woutT + (size_t)(n0 + wv * 32 + rowl) * 1024 + kcol;
    const int lofs = wv * 1024;

    gload16(ga,             &Al[0][lofs]);
    gload16(ga + 16 * 1024, &Al[0][lofs + 512]);
    gload16(gb,             &Bl[0][lofs]);
    gload16(gb + 16 * 1024, &Bl[0][lofs + 512]);
    asm volatile("s_waitcnt vmcnt(0)" ::: "memory");
    __builtin_amdgcn_s_barrier();

    for (int it = 0; it < 32; it++) {
        const int cur = it & 1;
        if (it + 1 < 32) {
            const int k0 = (it + 1) * 32;
            const int nxt = cur ^ 1;
            gload16(ga + k0,             &Al[nxt][lofs]);
            gload16(ga + k0 + 16 * 1024, &Al[nxt][lofs + 512]);
            gload16(gb + k0,             &Bl[nxt][lofs]);
            gload16(gb + k0 + 16 * 1024, &Bl[nxt][lofs + 512]);
        }
        short8 af[4], bfr[4];
        #pragma unroll
        for (int fm = 0; fm < 4; fm++)
            af[fm] = *(const short8*)&Al[cur][(wr + fm * 16 + l15) * 32 + g * 8];
        #pragma unroll
        for (int fn = 0; fn < 4; fn++)
            bfr[fn] = *(const short8*)&Bl[cur][(wc + fn * 16 + l15) * 32 + g * 8];
        #pragma unroll
        for (int fm = 0; fm < 4; fm++)
            #pragma unroll
            for (int fn = 0; fn < 4; fn++)
                acc[fm][fn] = mfma_bf16(af[fm], bfr[fn], acc[fm][fn]);
        asm volatile("s_waitcnt vmcnt(0)" ::: "memory");
        __builtin_amdgcn_s_barrier();
    }
    #pragma unroll
    for (int fm = 0; fm < 4; fm++)
        #pragma unroll
        for (int fn = 0; fn < 4; fn++)
            #pragma unroll
            for (int r = 0; r < 4; r++) {
                int row = m0 + wr + fm * 16 + g * 4 + r;
                int col = n0 + wc + fn * 16 + l15;
                out[(size_t)row * 1024 + col] = acc[fm][fn][r];
            }
}

// ---------------------------------------------------------------------------
extern "C" void kernel_launch(void* const* d_in, const int* in_sizes, int n_in,
                              void* d_out, int out_size, void* d_ws, size_t ws_size,
                              hipStream_t stream)
{
    const float* hidden = (const float*)d_in[0];
    const float* wqkv   = (const float*)d_in[1];
    const float* wout   = (const float*)d_in[2];
    float* out = (float*)d_out;

    const size_t NELEM = (size_t)2 * SEQ * HID;   // 4,194,304
    ushort* Qb    = (ushort*)d_ws;
    ushort* Kb    = Qb + NELEM;
    ushort* Vb    = Kb + NELEM;
    ushort* hbf   = Vb + NELEM;                   // hidden bf16; later reused as attn
    ushort* wqkvT = hbf + NELEM;                  // 3072*1024
    ushort* woutT = wqkvT + (size_t)3072 * 1024;  // 1024*1024
    ushort* attnb = hbf;                          // alias: lifetime disjoint

    convert_bf16_kernel<<<2048, 256, 0, stream>>>(hidden, hbf, (int)NELEM);
    transpose_bf16_kernel<<<dim3(48, 16), 256, 0, stream>>>(wqkv, wqkvT, 1024, 3072);
    transpose_bf16_kernel<<<dim3(16, 16), 256, 0, stream>>>(wout, woutT, 1024, 1024);
    qkv_rope_kernel<<<dim3(24, 16), 512, 0, stream>>>(hbf, wqkvT, Qb, Kb, Vb);
    attn_kernel<<<dim3(16, NHEADS, 2), 512, 0, stream>>>(Qb, Kb, Vb, attnb);
    out_proj_kernel<<<dim3(8, 32), 256, 0, stream>>>(attnb, woutT, out);
}

// Round 12
// 129.395 us; speedup vs baseline: 1.9143x; 1.9143x over previous
//
#include <hip/hip_runtime.h>

#define SEQ   2048
#define NHEADS 16
#define HDIM  64
#define HID   1024
#define ROT   32

typedef __attribute__((ext_vector_type(8))) short  short8;
typedef __attribute__((ext_vector_type(4))) float  floatx4;

__device__ __forceinline__ ushort f2bf(float f) {
    union { float f; uint u; } v; v.f = f;
    uint x = v.u;
    uint r = (x + 0x7FFFu + ((x >> 16) & 1u)) >> 16;
    return (ushort)r;
}

__device__ __forceinline__ float fexp2(float x) {
    return __builtin_amdgcn_exp2f(x);     // v_exp_f32 directly
}

__device__ __forceinline__ floatx4 mfma_bf16(short8 a, short8 b, floatx4 c) {
    return __builtin_amdgcn_mfma_f32_16x16x32_bf16(a, b, c, 0, 0, 0);
}

__device__ __forceinline__ void gload16(const ushort* g, ushort* l) {
    __builtin_amdgcn_global_load_lds(
        (const __attribute__((address_space(1))) void*)g,
        (__attribute__((address_space(3))) void*)l, 16, 0, 0);
}

// ---------------------------------------------------------------------------
// Pre-pass A: fp32 -> bf16 elementwise (hidden)
// ---------------------------------------------------------------------------
__global__ __launch_bounds__(256) void convert_bf16_kernel(
    const float* __restrict__ src, ushort* __restrict__ dst, int n)
{
    int i = (blockIdx.x * 256 + threadIdx.x) * 8;
    if (i >= n) return;
    float4 a = *(const float4*)(src + i);
    float4 b = *(const float4*)(src + i + 4);
    short8 v;
    v[0] = (short)f2bf(a.x); v[1] = (short)f2bf(a.y);
    v[2] = (short)f2bf(a.z); v[3] = (short)f2bf(a.w);
    v[4] = (short)f2bf(b.x); v[5] = (short)f2bf(b.y);
    v[6] = (short)f2bf(b.z); v[7] = (short)f2bf(b.w);
    *(short8*)(dst + i) = v;
}

// ---------------------------------------------------------------------------
// Pre-pass B: fp32 (K,N) -> bf16 (N,K) transpose-convert. Tile 64x64.
// ---------------------------------------------------------------------------
__global__ __launch_bounds__(256) void transpose_bf16_kernel(
    const float* __restrict__ src, ushort* __restrict__ dst, int K, int N)
{
    __shared__ ushort Tl[64 * 68];
    const int k0 = blockIdx.y * 64, n0 = blockIdx.x * 64;
    const int tid = threadIdx.x;
    #pragma unroll
    for (int i = 0; i < 4; i++) {
        int lin = tid + 256 * i;
        int row = lin >> 4;
        int c4  = (lin & 15) * 4;
        float4 v = *(const float4*)(src + (size_t)(k0 + row) * N + n0 + c4);
        uint2 u;
        u.x = (uint)f2bf(v.x) | ((uint)f2bf(v.y) << 16);
        u.y = (uint)f2bf(v.z) | ((uint)f2bf(v.w) << 16);
        *(uint2*)&Tl[row * 68 + c4] = u;
    }
    __syncthreads();
    #pragma unroll
    for (int j = 0; j < 2; j++) {
        int lin = tid + 256 * j;
        int n = lin >> 3, c = lin & 7;
        short8 v;
        #pragma unroll
        for (int u = 0; u < 8; u++) v[u] = (short)Tl[(c * 8 + u) * 68 + n];
        *(short8*)(dst + (size_t)(n0 + n) * K + k0 + c * 8) = v;
    }
}

// ---------------------------------------------------------------------------
// Kernel 1: qkv = hidden @ w_qkv (M=4096, N=3072, K=1024) bf16 inputs.
// 128(M) x 256(N) tile, 8 waves (512 thr, NO min-occupancy bound — r11's
// (512,6) was interpreted as CUDA min-blocks and capped VGPR at 40 -> spill).
// Round-9 2-phase pipelined double-buffer; 3 gload_lds/thread/iter.
// LDS 48KB -> 3 blocks/CU. Fused RoPE + head split. Q pre-scaled by
// 0.125*log2(e). Q,K (b,h,s,d); V (b,h,d,s).
// ---------------------------------------------------------------------------
__global__ __launch_bounds__(512) void qkv_rope_kernel(
    const ushort* __restrict__ hbf,     // (4096,1024) bf16
    const ushort* __restrict__ wqkvT,   // (3072,1024) bf16 (N,K)
    ushort* __restrict__ Qb, ushort* __restrict__ Kb, ushort* __restrict__ Vb)
{
    __shared__ ushort Al[2][4096];      // A tile 128x32
    __shared__ ushort Bl[2][8192];      // B tile 256x32
    const int tid  = threadIdx.x;
    const int lane = tid & 63;
    const int wv   = tid >> 6;          // 0..7
    const int g    = lane >> 4;
    const int l15  = lane & 15;

    // XCD-chunked remap over the 12(n) x 32(m) tile grid: each XCD owns a
    // 6(n) x 8(m) chunk (A 2MB + B 3MB ~ L2-resident).
    const int lin  = blockIdx.x + 12 * blockIdx.y;  // 0..383
    const int xcd  = lin & 7;
    const int slot = lin >> 3;                      // 0..47
    const int cxi  = xcd & 1, cyi = xcd >> 1;       // 2(n) x 4(m) chunks
    const int sx   = slot % 6, sy = slot / 6;       // 6 x 8
    const int n0   = (cxi * 6 + sx) * 256;
    const int m0   = (cyi * 8 + sy) * 128;

    const int wr = (wv >> 2) * 64;      // 0,64      (2 m-waves)
    const int wc = (wv & 3) * 64;       // 0..192    (4 n-waves)
    const int arow = tid >> 2;          // 0..127
    const int acol = (tid & 3) * 8;

    floatx4 acc[4][4];
    #pragma unroll
    for (int a = 0; a < 4; a++)
        #pragma unroll
        for (int bq = 0; bq < 4; bq++)
            acc[a][bq] = floatx4{0.f, 0.f, 0.f, 0.f};

    const ushort* ga  = hbf   + (size_t)(m0 + arow) * 1024 + acol;
    const ushort* gb0 = wqkvT + (size_t)(n0 + arow) * 1024 + acol;
    const ushort* gb1 = gb0 + (size_t)128 * 1024;
    const int wofs = wv * 512;          // wave-uniform LDS base (ushorts)

    auto stage = [&](int t, int buf) {
        const int k0 = t * 32;
        gload16(ga  + k0, &Al[buf][wofs]);
        gload16(gb0 + k0, &Bl[buf][wofs]);
        gload16(gb1 + k0, &Bl[buf][4096 + wofs]);
    };

    stage(0, 0);
    asm volatile("s_waitcnt vmcnt(0)" ::: "memory");
    __builtin_amdgcn_s_barrier();

    for (int it = 0; it < 32; it++) {
        const int cur = it & 1;
        if (it + 1 < 32) stage(it + 1, cur ^ 1);
        short8 af[4], bfr[4];
        #pragma unroll
        for (int fm = 0; fm < 4; fm++)
            af[fm] = *(const short8*)&Al[cur][(wr + fm * 16 + l15) * 32 + g * 8];
        #pragma unroll
        for (int fn = 0; fn < 4; fn++)
            bfr[fn] = *(const short8*)&Bl[cur][(wc + fn * 16 + l15) * 32 + g * 8];
        #pragma unroll
        for (int fm = 0; fm < 4; fm++)
            #pragma unroll
            for (int fn = 0; fn < 4; fn++)
                acc[fm][fn] = mfma_bf16(af[fm], bfr[fn], acc[fm][fn]);
        asm volatile("s_waitcnt vmcnt(0)" ::: "memory");
        __builtin_amdgcn_s_barrier();
    }

    // epilogue: per-wave output rows m0+wr+fm*16+g*4+r, cols n0+wc+fn*16+l15
    #pragma unroll
    for (int fn = 0; fn < 4; fn++) {
        const int c    = n0 + wc + fn * 16 + l15;
        const int mp   = c / 384;
        const int rem  = c - mp * 384;
        const int tsel = rem >> 7;                    // 0=q 1=k 2=v
        const int j    = (rem >> 6) & 1;
        const int d    = rem & 63;
        const int head = mp * 2 + j;
        ushort* basep = (tsel == 0) ? Qb : (tsel == 1) ? Kb : Vb;
        const bool rope = (tsel < 2) && (d < ROT);
        // Q carries 1/sqrt(64) * log2(e) so attention uses exp2 directly
        const float qscale = (tsel == 0) ? 0.18033688011112042f : 1.0f;
        float freq = 0.f;
        if (rope) {
            freq = exp2f((float)(d >> 1) * -0.830482023721841f);
        }
        #pragma unroll
        for (int fm = 0; fm < 4; fm++) {
            #pragma unroll
            for (int r = 0; r < 4; r++) {
                int row = m0 + wr + fm * 16 + g * 4 + r;
                int bb  = row >> 11;
                int s   = row & 2047;
                float val = acc[fm][fn][r];
                float pv  = __shfl_xor(val, 1, 64);
                float outv = val;
                if (rope) {
                    float ang = (float)s * freq;
                    float sn, cs;
                    __sincosf(ang, &sn, &cs);
                    outv = ((d & 1) == 0) ? (val * cs - pv * sn)
                                          : (val * cs + pv * sn);
                }
                outv *= qscale;
                size_t off;
                if (tsel == 2)
                    off = ((size_t)(bb * NHEADS + head) * HDIM + d) * SEQ + s;
                else
                    off = ((size_t)(bb * NHEADS + head) * SEQ + s) * HDIM + d;
                basep[off] = f2bf(outv);
            }
        }
    }
}

// ---------------------------------------------------------------------------
// Kernel 2: flash attention, causal. 512 threads = 8 waves x 16 q-rows
// (Q tile 128), KV tiles 64. Complementary-qb pairing; 2-deep register
// prefetch + LDS double-buffer; exp2-domain softmax with per-lane defer-max
// (cross-lane reduces only on rescale) and epilogue-deferred l-sum.
// ---------------------------------------------------------------------------
__global__ __launch_bounds__(512, 4) void attn_kernel(
    const ushort* __restrict__ Qb, const ushort* __restrict__ Kb,
    const ushort* __restrict__ Vb, ushort* __restrict__ attn)
{
    __shared__ ushort Kl[2][64 * 72];      // [key][d], stride 72
    __shared__ ushort Vt[2][64 * 72];      // [d][key], stride 72

    const int tid  = threadIdx.x;
    const int lane = tid & 63;
    const int wv   = tid >> 6;             // 0..7
    const int g    = lane >> 4;
    const int l15  = lane & 15;

    const int l    = blockIdx.x + 16 * blockIdx.y + 256 * blockIdx.z;
    const int half = l >> 8;
    const int xx   = l & 15;
    const int hh   = (l >> 4) & 15;
    const int qb   = half ? xx : 15 - xx;
    const int bb   = half;

    const int q0 = qb * 128;
    const int wq = wv * 16;
    const size_t kvbase = (size_t)(bb * NHEADS + hh) * SEQ * HDIM;

    const int srow = tid >> 3;             // 0..63 staging row
    const int sch  = (tid & 7) * 8;        // staging col (ushort)

    short8 qreg[2];
    #pragma unroll
    for (int ks = 0; ks < 2; ks++)
        qreg[ks] = *(const short8*)(Qb + kvbase +
            (size_t)(q0 + wq + l15) * HDIM + ks * 32 + g * 8);

    float m = -__builtin_inff();
    float lsum = 0.f;                      // per-lane partial (16 keys/row)
    floatx4 of[4];
    #pragma unroll
    for (int df = 0; df < 4; df++) of[df] = floatx4{0.f, 0.f, 0.f, 0.f};

    const int nt = 2 * qb + 2;             // always even

    auto load_tile = [&](int tt, short8& kr, short8& vr) {
        const int kv = tt * 64;
        kr = *(const short8*)(Kb + kvbase + (size_t)(kv + srow) * HDIM + sch);
        vr = *(const short8*)(Vb + kvbase + (size_t)srow * SEQ + kv + sch);
    };
    auto write_tile = [&](int buf, short8& kr, short8& vr) {
        *(short8*)&Kl[buf][srow * 72 + sch] = kr;
        *(short8*)&Vt[buf][srow * 72 + sch] = vr;
    };
    auto compute_tile = [&](int t, const ushort* Kc, const ushort* Vc) {
        const int kv0 = t * 64;
        if (kv0 > q0 + wq + 15) return;    // fully-masked for this wave
        // QK^T (swapped): sf[kf], lane l15 = q-row, key = kv0 + kf*16 + g*4 + r
        floatx4 sf[4];
        __builtin_amdgcn_s_setprio(1);
        #pragma unroll
        for (int kf = 0; kf < 4; kf++) {
            short8 kr0 = *(const short8*)&Kc[(kf * 16 + l15) * 72 + g * 8];
            short8 kr1 = *(const short8*)&Kc[(kf * 16 + l15) * 72 + 32 + g * 8];
            floatx4 s = floatx4{0.f, 0.f, 0.f, 0.f};
            s = mfma_bf16(kr0, qreg[0], s);
            s = mfma_bf16(kr1, qreg[1], s);
            sf[kf] = s;
        }
        __builtin_amdgcn_s_setprio(0);

        const bool diag = (kv0 + 63 > q0 + wq);   // wave-uniform
        const int qg = q0 + wq + l15;
        float tmax = -__builtin_inff();
        if (diag) {
            #pragma unroll
            for (int kf = 0; kf < 4; kf++) {
                #pragma unroll
                for (int r = 0; r < 4; r++) {
                    int key = kv0 + kf * 16 + g * 4 + r;
                    float x = sf[kf][r];
                    if (key > qg) x = -1e9f;
                    sf[kf][r] = x;
                    tmax = fmaxf(tmax, x);
                }
            }
        } else {
            #pragma unroll
            for (int kf = 0; kf < 4; kf++)
                #pragma unroll
                for (int r = 0; r < 4; r++)
                    tmax = fmaxf(tmax, sf[kf][r]);
        }
        // per-lane defer-max: no cross-lane traffic in the common case
        if (!__all(tmax <= m + 8.0f)) {
            tmax = fmaxf(tmax, __shfl_xor(tmax, 16, 64));
            tmax = fmaxf(tmax, __shfl_xor(tmax, 32, 64));
            float mn = fmaxf(m, tmax);
            float f  = fexp2(m - mn);
            m = mn;
            lsum *= f;
            #pragma unroll
            for (int r = 0; r < 4; r++) {
                float fr = __shfl(f, g * 4 + r, 64);
                #pragma unroll
                for (int df = 0; df < 4; df++)
                    of[df][r] *= fr;
            }
        }
        float rs = 0.f;
        #pragma unroll
        for (int kf = 0; kf < 4; kf++) {
            #pragma unroll
            for (int r = 0; r < 4; r++) {
                float p = fexp2(sf[kf][r] - m);
                sf[kf][r] = p;
                rs += p;
            }
        }
        lsum += rs;
        // pack P into lane-local A-frags via v_cvt_pk_bf16_f32
        short8 pa[2];
        #pragma unroll
        for (int ks = 0; ks < 2; ks++) {
            union { short8 s; uint u[4]; } pu;
            #pragma unroll
            for (int w = 0; w < 4; w++) {
                const int kf = 2 * ks + (w >> 1);
                float lo = sf[kf][(w & 1) * 2 + 0];
                float hi = sf[kf][(w & 1) * 2 + 1];
                asm("v_cvt_pk_bf16_f32 %0, %1, %2"
                    : "=v"(pu.u[w]) : "v"(lo), "v"(hi));
            }
            pa[ks] = pu.s;
        }
        // PV
        __builtin_amdgcn_s_setprio(1);
        #pragma unroll
        for (int df = 0; df < 4; df++) {
            #pragma unroll
            for (int ks = 0; ks < 2; ks++) {
                const int vb = (df * 16 + l15) * 72 + ks * 32 + g * 4;
                uint2 v0 = *(const uint2*)&Vc[vb];
                uint2 v1 = *(const uint2*)&Vc[vb + 16];
                union { short8 s; uint4 u; } vv;
                vv.u.x = v0.x; vv.u.y = v0.y; vv.u.z = v1.x; vv.u.w = v1.y;
                of[df] = mfma_bf16(pa[ks], vv.s, of[df]);
            }
        }
        __builtin_amdgcn_s_setprio(0);
    };

    short8 kA, vA, kB, vB;
    load_tile(0, kA, vA);
    if (nt > 1) load_tile(1, kB, vB);
    write_tile(0, kA, vA);
    __syncthreads();

    for (int t = 0; t < nt; t += 2) {
        if (t + 2 < nt) load_tile(t + 2, kA, vA);
        compute_tile(t, Kl[0], Vt[0]);
        write_tile(1, kB, vB);
        __syncthreads();
        if (t + 3 < nt) load_tile(t + 3, kB, vB);
        compute_tile(t + 1, Kl[1], Vt[1]);
        if (t + 2 < nt) write_tile(0, kA, vA);
        __syncthreads();
    }

    // epilogue: reduce l across g-lanes once, O /= l, store attn (b,s,H) bf16
    lsum += __shfl_xor(lsum, 16, 64);
    lsum += __shfl_xor(lsum, 32, 64);
    #pragma unroll
    for (int r = 0; r < 4; r++) {
        float lr = __shfl(lsum, g * 4 + r, 64);
        float inv = 1.0f / lr;
        int q = q0 + wq + g * 4 + r;
        #pragma unroll
        for (int df = 0; df < 4; df++)
            attn[((size_t)bb * SEQ + q) * HID + hh * 64 + df * 16 + l15] =
                f2bf(of[df][r] * inv);
    }
}

// ---------------------------------------------------------------------------
// Kernel 3: out = attn @ w_out (M=4096, N=1024, K=1024), 2-phase pipelined
// double-buffer (round-9 form), fp32 output.
// ---------------------------------------------------------------------------
__global__ __launch_bounds__(256) void out_proj_kernel(
    const ushort* __restrict__ attn,    // (4096,1024) bf16
    const ushort* __restrict__ woutT,   // (1024,1024) bf16 (N,K)
    float* __restrict__ out)
{
    __shared__ ushort Al[2][128 * 32];
    __shared__ ushort Bl[2][128 * 32];
    const int tid  = threadIdx.x;
    const int lane = tid & 63;
    const int wv   = tid >> 6;
    const int g    = lane >> 4;
    const int l15  = lane & 15;

    const int lin  = blockIdx.x + 8 * blockIdx.y;   // 0..255
    const int xcd  = lin & 7;
    const int slot = lin >> 3;                      // 0..31
    const int cxi  = xcd & 1, cyi = xcd >> 1;
    const int sx   = slot & 3, sy = slot >> 2;      // 4x8
    const int n0   = (cxi * 4 + sx) * 128;
    const int m0   = (cyi * 8 + sy) * 128;

    const int wr = (wv >> 1) * 64;
    const int wc = (wv & 1) * 64;
    const int rowl = lane >> 2;
    const int kcol = (lane & 3) * 8;

    floatx4 acc[4][4];
    #pragma unroll
    for (int a = 0; a < 4; a++)
        #pragma unroll
        for (int bq = 0; bq < 4; bq++)
            acc[a][bq] = floatx4{0.f, 0.f, 0.f, 0.f};

    const ushort* ga = attn  + (size_t)(m0 + wv * 32 + rowl) * 1024 + kcol;
    const ushort* gb = woutT + (size_t)(n0 + wv * 32 + rowl) * 1024 + kcol;
    const int lofs = wv * 1024;

    gload16(ga,             &Al[0][lofs]);
    gload16(ga + 16 * 1024, &Al[0][lofs + 512]);
    gload16(gb,             &Bl[0][lofs]);
    gload16(gb + 16 * 1024, &Bl[0][lofs + 512]);
    asm volatile("s_waitcnt vmcnt(0)" ::: "memory");
    __builtin_amdgcn_s_barrier();

    for (int it = 0; it < 32; it++) {
        const int cur = it & 1;
        if (it + 1 < 32) {
            const int k0 = (it + 1) * 32;
            const int nxt = cur ^ 1;
            gload16(ga + k0,             &Al[nxt][lofs]);
            gload16(ga + k0 + 16 * 1024, &Al[nxt][lofs + 512]);
            gload16(gb + k0,             &Bl[nxt][lofs]);
            gload16(gb + k0 + 16 * 1024, &Bl[nxt][lofs + 512]);
        }
        short8 af[4], bfr[4];
        #pragma unroll
        for (int fm = 0; fm < 4; fm++)
            af[fm] = *(const short8*)&Al[cur][(wr + fm * 16 + l15) * 32 + g * 8];
        #pragma unroll
        for (int fn = 0; fn < 4; fn++)
            bfr[fn] = *(const short8*)&Bl[cur][(wc + fn * 16 + l15) * 32 + g * 8];
        #pragma unroll
        for (int fm = 0; fm < 4; fm++)
            #pragma unroll
            for (int fn = 0; fn < 4; fn++)
                acc[fm][fn] = mfma_bf16(af[fm], bfr[fn], acc[fm][fn]);
        asm volatile("s_waitcnt vmcnt(0)" ::: "memory");
        __builtin_amdgcn_s_barrier();
    }
    #pragma unroll
    for (int fm = 0; fm < 4; fm++)
        #pragma unroll
        for (int fn = 0; fn < 4; fn++)
            #pragma unroll
            for (int r = 0; r < 4; r++) {
                int row = m0 + wr + fm * 16 + g * 4 + r;
                int col = n0 + wc + fn * 16 + l15;
                out[(size_t)row * 1024 + col] = acc[fm][fn][r];
            }
}

// ---------------------------------------------------------------------------
extern "C" void kernel_launch(void* const* d_in, const int* in_sizes, int n_in,
                              void* d_out, int out_size, void* d_ws, size_t ws_size,
                              hipStream_t stream)
{
    const float* hidden = (const float*)d_in[0];
    const float* wqkv   = (const float*)d_in[1];
    const float* wout   = (const float*)d_in[2];
    float* out = (float*)d_out;

    const size_t NELEM = (size_t)2 * SEQ * HID;   // 4,194,304
    ushort* Qb    = (ushort*)d_ws;
    ushort* Kb    = Qb + NELEM;
    ushort* Vb    = Kb + NELEM;
    ushort* hbf   = Vb + NELEM;                   // hidden bf16; later reused as attn
    ushort* wqkvT = hbf + NELEM;                  // 3072*1024
    ushort* woutT = wqkvT + (size_t)3072 * 1024;  // 1024*1024
    ushort* attnb = hbf;                          // alias: lifetime disjoint

    convert_bf16_kernel<<<2048, 256, 0, stream>>>(hidden, hbf, (int)NELEM);
    transpose_bf16_kernel<<<dim3(48, 16), 256, 0, stream>>>(wqkv, wqkvT, 1024, 3072);
    transpose_bf16_kernel<<<dim3(16, 16), 256, 0, stream>>>(wout, woutT, 1024, 1024);
    qkv_rope_kernel<<<dim3(12, 32), 512, 0, stream>>>(hbf, wqkvT, Qb, Kb, Vb);
    attn_kernel<<<dim3(16, NHEADS, 2), 512, 0, stream>>>(Qb, Kb, Vb, attnb);
    out_proj_kernel<<<dim3(8, 32), 256, 0, stream>>>(attnb, woutT, out);
}